// Round 7
// baseline (380.451 us; speedup 1.0000x reference)
//
#include <hip/hip_runtime.h>

// EdgeFeature kNN (DGCNN): B=4, D=64, N=4096, K=16, fp32 in/out.
// Ranking replicates the numpy fp32 reference pipeline bit-exactly:
//   sq_n  = numpy pairwise_sum (8-accumulator unroll) of fl(x_d^2)
//   dot   = sequential over d of  a = fmaf(x_d, y_d, a)   (einsum axpy w/ FMA)
//   d2    = fl(fl(sq_n + sq_m) - fl(2*dot));  dist = fl(sqrt(max(d2,0)))
//   order = (dist_f32, index) lexicographic (stable top_k tie-break)
// Key pack: (dist_bits << 32) | m -> u64; positive-finite-f64 bit order ==
// u64 order, so CE can be f64 min/max (2 instr) or u64 cmp+cndmask (5 instr).
// Sentinel 0x7FEFFFFFFFFFFFFF (DBL_MAX bits) > any real key in BOTH orders.
//
// R14 (from R13: VALUBusy ~95% -> issue-bound; occupancy lever was null;
//      VGPR=64 -> compiler STILL rematerializes the query row):
//   * v_pk_fma_f32 with op_sel broadcast: query stored as f32x2 xp[32]
//     {x_2k, x_2k+1} (64 VGPRs -- NOT R12's 128-reg duplicated array).
//     Even d: op_sel_hi:[0,1,1] broadcasts src0.lo; odd d: op_sel:[1,0,0]
//     op_sel_hi:[1,1,1] broadcasts src0.hi. Candidate pairs come straight
//     from ds_read_b128. Per-candidate d-chain order unchanged -> exact.
//     FMA instrs per 8-cand group: 512 -> 256.
//   * CE-primitive A/B: chunks 0-15 use f64 min/max CE, chunks 16-31 use
//     u64 cmp+cndmask CE (identical network + output bits). Per-dispatch
//     dur_us resolves the v_min_f64 issue-rate question.
//   * __launch_bounds__(512, 2): allow up to ~256 VGPR so xp can stay
//     resident (occupancy is not the binding constraint).

#define BATCH 4
#define DIMS 64
#define NPTS 4096
#define KNN 16
#define NCHUNK 32
#define CHLEN 128      // NPTS / NCHUNK
#define GSZ 8          // candidates per group
#define RN (BATCH * NPTS)
#define MLANES 8       // merge lanes per row
#define MCH (NCHUNK / MLANES)
#define PBLK 512       // partial-kernel block size

typedef unsigned long long u64;
typedef unsigned int u32;
typedef float f32x2 __attribute__((ext_vector_type(2)));
typedef float f32x4 __attribute__((ext_vector_type(4)));

#define SENT 0x7FEFFFFFFFFFFFFFULL

// compare-exchange on packed keys; F64 uses v_min/max_f64, else u64 ladder
template <bool F64>
__device__ __forceinline__ void ce(u64& a, u64& b) {
    if (F64) {
        double da = __longlong_as_double((long long)a);
        double db = __longlong_as_double((long long)b);
        double lo = fmin(da, db), hi = fmax(da, db);
        a = (u64)__double_as_longlong(lo);
        b = (u64)__double_as_longlong(hi);
    } else {
        bool lt = a < b;
        u64 lo = lt ? a : b;
        u64 hi = lt ? b : a;
        a = lo;
        b = hi;
    }
}
template <bool F64>
__device__ __forceinline__ u64 keymin(u64 a, u64 b) {
    if (F64) {
        double m = fmin(__longlong_as_double((long long)a),
                        __longlong_as_double((long long)b));
        return (u64)__double_as_longlong(m);
    } else {
        return a < b ? a : b;
    }
}

// ---- kernel 0: per-point squared norm, numpy pairwise_sum order ---------
__global__ __launch_bounds__(256) void ef_sq_kernel(const float* __restrict__ pc,
                                                    float* __restrict__ sq) {
    int gid = blockIdx.x * 256 + threadIdx.x;     // b*NPTS + n
    int b = gid >> 12;
    int n = gid & (NPTS - 1);
    const float* p = pc + (size_t)b * DIMS * NPTS + n;
    float r[8];
#pragma unroll
    for (int j = 0; j < 8; ++j) {
        float v = p[(size_t)j * NPTS];
        r[j] = __fmul_rn(v, v);
    }
#pragma unroll
    for (int i = 8; i < DIMS; i += 8) {
#pragma unroll
        for (int j = 0; j < 8; ++j) {
            float v = p[(size_t)(i + j) * NPTS];
            r[j] = __fadd_rn(r[j], __fmul_rn(v, v));
        }
    }
    float t01 = __fadd_rn(r[0], r[1]);
    float t23 = __fadd_rn(r[2], r[3]);
    float t45 = __fadd_rn(r[4], r[5]);
    float t67 = __fadd_rn(r[6], r[7]);
    sq[gid] = __fadd_rn(__fadd_rn(t01, t23), __fadd_rn(t45, t67));
}

// ---- kernel 0b: transpose pc[b][d][m] -> pcT[(b*N+m)*64+d] --------------
__global__ __launch_bounds__(256) void ef_transpose(const float* __restrict__ pc,
                                                    float* __restrict__ pcT) {
    __shared__ float smT[DIMS][65];               // 65: conflict-free both phases
    int tid = threadIdx.x;
    int m0 = blockIdx.x * 64;
    int b = blockIdx.y;
    const float* pcb = pc + (size_t)b * DIMS * NPTS;
#pragma unroll
    for (int i = 0; i < 16; ++i) {                // load: coalesced over m
        int idx = i * 256 + tid;
        int d = idx >> 6;
        int m = idx & 63;
        smT[d][m] = pcb[(size_t)d * NPTS + m0 + m];
    }
    __syncthreads();
#pragma unroll
    for (int i = 0; i < 16; ++i) {                // store: coalesced over d
        int idx = i * 256 + tid;
        int m = idx >> 6;
        int d = idx & 63;
        pcT[((size_t)b * NPTS + m0 + m) * DIMS + d] = smT[d][m];
    }
}

// ---- kernel 1: per-(row, chunk) partial top-16, LDS-staged candidates ---
// v_pk_fma_f32 with op_sel broadcast of the query scalar (see header).
#define SHUF2(v, a, b) __builtin_shufflevector(v, v, a, b)
#define PKFMA_LO(acc, xv, cv)                                                 \
    asm("v_pk_fma_f32 %0, %1, %2, %0 op_sel:[0,0,0] op_sel_hi:[0,1,1]"        \
        : "+v"(acc) : "v"(xv), "v"(cv))
#define PKFMA_HI(acc, xv, cv)                                                 \
    asm("v_pk_fma_f32 %0, %1, %2, %0 op_sel:[1,0,0] op_sel_hi:[1,1,1]"        \
        : "+v"(acc) : "v"(xv), "v"(cv))

template <bool F64>
__global__ __launch_bounds__(PBLK, 2) void ef_knn_partial(const float* __restrict__ pc,
                                                          const float* __restrict__ sq,
                                                          u64* __restrict__ pKey,
                                                          int c0) {
    __shared__ float tile[DIMS][CHLEN];           // 32 KB candidate tile
    __shared__ float tileSq[CHLEN];
    int tid = threadIdx.x;
    int r = blockIdx.x * PBLK + tid;              // global row: b*NPTS + n
    int c = c0 + blockIdx.y;
    int b = (blockIdx.x * PBLK) >> 12;            // uniform per block
    int n = r & (NPTS - 1);
    int m0 = c * CHLEN;
    const float* pcb = pc + (size_t)b * DIMS * NPTS;

    // query row as 32 pairs {x_2k, x_2k+1}: 64 VGPRs, same as scalar xr[64]
    f32x2 xp[DIMS / 2];
#pragma unroll
    for (int k = 0; k < DIMS / 2; ++k) {
        float e = pcb[(size_t)(2 * k) * NPTS + n];        // coalesced
        float o = pcb[(size_t)(2 * k + 1) * NPTS + n];
        xp[k] = (f32x2){e, o};
    }
    float sqn = sq[r];

    // stage candidate tile [64][128] + its sq row (coalesced float4)
#pragma unroll
    for (int i = 0; i < 4; ++i) {
        int idx = tid + i * PBLK;                 // float4 slot, 2048 total
        int d = idx >> 5;                         // 32 float4 per row
        int mq = idx & 31;
        float4 v = *(const float4*)(pcb + (size_t)d * NPTS + m0 + mq * 4);
        *(float4*)&tile[d][mq * 4] = v;
    }
    if (tid < CHLEN / 4)
        *(float4*)&tileSq[tid * 4] =
            *(const float4*)(sq + (size_t)b * NPTS + m0 + tid * 4);
    __syncthreads();

    u64 key[KNN];
#pragma unroll
    for (int j = 0; j < KNN; ++j) key[j] = SENT;

    for (int g = 0; g < CHLEN; g += GSZ) {
        f32x2 accp[4];
#pragma unroll
        for (int j = 0; j < 4; ++j) accp[j] = (f32x2){0.f, 0.f};
        // per k: d=2k (broadcast xp[k].lo) then d=2k+1 (broadcast xp[k].hi);
        // each candidate's d-chain stays sequential -> bit-exact.
#pragma unroll
        for (int k = 0; k < DIMS / 2; ++k) {
            f32x4 qe0 = *(const f32x4*)&tile[2 * k][g];
            f32x4 qe1 = *(const f32x4*)&tile[2 * k][g + 4];
            f32x4 qo0 = *(const f32x4*)&tile[2 * k + 1][g];
            f32x4 qo1 = *(const f32x4*)&tile[2 * k + 1][g + 4];
            f32x2 xk = xp[k];
            PKFMA_LO(accp[0], xk, SHUF2(qe0, 0, 1));
            PKFMA_LO(accp[1], xk, SHUF2(qe0, 2, 3));
            PKFMA_LO(accp[2], xk, SHUF2(qe1, 0, 1));
            PKFMA_LO(accp[3], xk, SHUF2(qe1, 2, 3));
            PKFMA_HI(accp[0], xk, SHUF2(qo0, 0, 1));
            PKFMA_HI(accp[1], xk, SHUF2(qo0, 2, 3));
            PKFMA_HI(accp[2], xk, SHUF2(qo1, 0, 1));
            PKFMA_HI(accp[3], xk, SHUF2(qo1, 2, 3));
        }
        float4 sq_lo = *(const float4*)&tileSq[g];
        float4 sq_hi = *(const float4*)&tileSq[g + 4];
        float sqv[GSZ] = {sq_lo.x, sq_lo.y, sq_lo.z, sq_lo.w,
                          sq_hi.x, sq_hi.y, sq_hi.z, sq_hi.w};
        u64 s[GSZ];
#pragma unroll
        for (int j = 0; j < GSZ; ++j) {
            int m = m0 + g + j;
            float a = accp[j / 2][j % 2];          // compile-time index
            float t1 = __fadd_rn(sqn, sqv[j]);
            float d2 = __fsub_rn(t1, __fmul_rn(2.0f, a));
            float dist = __fsqrt_rn(fmaxf(d2, 0.f));
            u64 cu = ((u64)__float_as_uint(dist) << 32) | (u64)(u32)m;
            s[j] = (m == n) ? SENT : cu;           // self -> +max sentinel
        }
        // sort8: Batcher odd-even mergesort, 19 CE (exact total order)
        ce<F64>(s[0], s[1]); ce<F64>(s[2], s[3]); ce<F64>(s[4], s[5]); ce<F64>(s[6], s[7]);
        ce<F64>(s[0], s[2]); ce<F64>(s[1], s[3]); ce<F64>(s[4], s[6]); ce<F64>(s[5], s[7]);
        ce<F64>(s[1], s[2]); ce<F64>(s[5], s[6]);
        ce<F64>(s[0], s[4]); ce<F64>(s[1], s[5]); ce<F64>(s[2], s[6]); ce<F64>(s[3], s[7]);
        ce<F64>(s[2], s[4]); ce<F64>(s[3], s[5]);
        ce<F64>(s[1], s[2]); ce<F64>(s[3], s[4]); ce<F64>(s[5], s[6]);
        // bitonic half-clean: merge sorted-8 into sorted key[16]
#pragma unroll
        for (int j = 8; j < 16; ++j) key[j] = keymin<F64>(key[j], s[15 - j]);
        // bitonic clean of 16: stages 8,4,2,1
#pragma unroll
        for (int st = 8; st >= 1; st >>= 1) {
#pragma unroll
            for (int j = 0; j < KNN; ++j) {
                if ((j & st) == 0) ce<F64>(key[j], key[j | st]);
            }
        }
    }

    // layout [c][r][j]: lane writes 128 B contiguous, wave covers 8 KB
    u64* dst = pKey + ((size_t)c * RN + r) * KNN;
#pragma unroll
    for (int j = 0; j < KNN; ++j) dst[j] = key[j];
}

// ---- kernel 2: merge 32 sorted partial lists per row, 8 lanes per row ---
__global__ __launch_bounds__(256) void ef_knn_merge(const u64* __restrict__ pKey,
                                                    float* __restrict__ outIdxF) {
    int t = blockIdx.x * 256 + threadIdx.x;       // rows * MLANES = 131072
    int r = t >> 3;
    int s = t & 7;
    double key[KNN];
    {
        const u64* src = pKey + ((size_t)(s * MCH) * RN + r) * KNN;
#pragma unroll
        for (int j = 0; j < KNN; ++j)
            key[j] = __longlong_as_double((long long)src[j]);
    }
    for (int ci = 1; ci < MCH; ++ci) {
        const u64* src = pKey + ((size_t)(s * MCH + ci) * RN + r) * KNN;
        double v[KNN];
#pragma unroll
        for (int j = 0; j < KNN; ++j)
            v[j] = __longlong_as_double((long long)src[j]);
#pragma unroll
        for (int j = 0; j < KNN; ++j) key[j] = fmin(key[j], v[KNN - 1 - j]);
#pragma unroll
        for (int st = 8; st >= 1; st >>= 1) {
#pragma unroll
            for (int j = 0; j < KNN; ++j) {
                if ((j & st) == 0) {
                    double a = key[j], d = key[j | st];
                    key[j] = fmin(a, d);
                    key[j | st] = fmax(a, d);
                }
            }
        }
    }
#pragma unroll
    for (int mask = 1; mask <= 4; mask <<= 1) {
        double oth[KNN];
#pragma unroll
        for (int j = 0; j < KNN; ++j) oth[j] = __shfl_xor(key[j], mask, 64);
#pragma unroll
        for (int j = 0; j < KNN; ++j) key[j] = fmin(key[j], oth[KNN - 1 - j]);
#pragma unroll
        for (int st = 8; st >= 1; st >>= 1) {
#pragma unroll
            for (int j = 0; j < KNN; ++j) {
                if ((j & st) == 0) {
                    double a = key[j], d = key[j | st];
                    key[j] = fmin(a, d);
                    key[j | st] = fmax(a, d);
                }
            }
        }
    }
    if (s == 0) {
        float* dstf = outIdxF + (size_t)r * KNN;
#pragma unroll
        for (int j = 0; j < KNN; ++j)
            dstf[j] = (float)(u32)((u64)__double_as_longlong(key[j]) & 0xFFFFFFFFu);
    }
}

// ---- kernel 3: edge features, pcT rows, 4 k per thread, float4 I/O ------
__global__ __launch_bounds__(256) void ef_edge_kernelT(const float* __restrict__ pcT,
                                                       const float* __restrict__ idxF,
                                                       float* __restrict__ out) {
    int t = blockIdx.x * 256 + threadIdx.x;        // B*N*K/4 = 65536
    int b = t >> 14;                               // N*K/4 = 16384
    int rem = t & 16383;
    int n = rem >> 2;
    int k0 = (rem & 3) * 4;
    float4 i4 = *(const float4*)(idxF + (((size_t)(b << 12) + n) << 4) + k0);
    int m0 = (int)i4.x, m1 = (int)i4.y, m2 = (int)i4.z, m3 = (int)i4.w;
    const float4* cr  = (const float4*)(pcT + ((size_t)(b << 12) + n)  * DIMS);
    const float4* nr0 = (const float4*)(pcT + ((size_t)(b << 12) + m0) * DIMS);
    const float4* nr1 = (const float4*)(pcT + ((size_t)(b << 12) + m1) * DIMS);
    const float4* nr2 = (const float4*)(pcT + ((size_t)(b << 12) + m2) * DIMS);
    const float4* nr3 = (const float4*)(pcT + ((size_t)(b << 12) + m3) * DIMS);
    float* ob = out + (size_t)b * 2 * DIMS * NPTS * KNN + (size_t)n * KNN + k0;
#pragma unroll
    for (int q = 0; q < DIMS / 4; ++q) {
        float4 c4 = cr[q];
        float4 a0 = nr0[q], a1 = nr1[q], a2 = nr2[q], a3 = nr3[q];
        float cv, nv0, nv1, nv2, nv3;
        float4 st;
        cv = c4.x; nv0 = a0.x; nv1 = a1.x; nv2 = a2.x; nv3 = a3.x;
        st = make_float4(cv, cv, cv, cv);
        *(float4*)(ob + (size_t)(4 * q + 0) * (NPTS * KNN)) = st;
        st = make_float4(nv0 - cv, nv1 - cv, nv2 - cv, nv3 - cv);
        *(float4*)(ob + (size_t)(DIMS + 4 * q + 0) * (NPTS * KNN)) = st;
        cv = c4.y; nv0 = a0.y; nv1 = a1.y; nv2 = a2.y; nv3 = a3.y;
        st = make_float4(cv, cv, cv, cv);
        *(float4*)(ob + (size_t)(4 * q + 1) * (NPTS * KNN)) = st;
        st = make_float4(nv0 - cv, nv1 - cv, nv2 - cv, nv3 - cv);
        *(float4*)(ob + (size_t)(DIMS + 4 * q + 1) * (NPTS * KNN)) = st;
        cv = c4.z; nv0 = a0.z; nv1 = a1.z; nv2 = a2.z; nv3 = a3.z;
        st = make_float4(cv, cv, cv, cv);
        *(float4*)(ob + (size_t)(4 * q + 2) * (NPTS * KNN)) = st;
        st = make_float4(nv0 - cv, nv1 - cv, nv2 - cv, nv3 - cv);
        *(float4*)(ob + (size_t)(DIMS + 4 * q + 2) * (NPTS * KNN)) = st;
        cv = c4.w; nv0 = a0.w; nv1 = a1.w; nv2 = a2.w; nv3 = a3.w;
        st = make_float4(cv, cv, cv, cv);
        *(float4*)(ob + (size_t)(4 * q + 3) * (NPTS * KNN)) = st;
        st = make_float4(nv0 - cv, nv1 - cv, nv2 - cv, nv3 - cv);
        *(float4*)(ob + (size_t)(DIMS + 4 * q + 3) * (NPTS * KNN)) = st;
    }
}

// ---- kernel 3 fallback: edge features straight from pc ------------------
__global__ __launch_bounds__(256) void ef_edge_kernel(const float* __restrict__ pc,
                                                      const float* __restrict__ idxF,
                                                      float* __restrict__ out) {
    int gid = blockIdx.x * 256 + threadIdx.x;      // B*N*K = 262144
    int b = gid >> 16;                             // N*K = 65536
    int nk = gid & 65535;
    int n = nk >> 4;
    int m = (int)idxF[gid];
    const float* pcb = pc + (size_t)b * DIMS * NPTS;
    float* ob = out + (size_t)b * 2 * DIMS * NPTS * KNN;
#pragma unroll
    for (int d = 0; d < DIMS; ++d) {
        float cv = pcb[(size_t)d * NPTS + n];
        float nv = pcb[(size_t)d * NPTS + m];
        ob[(size_t)d * (NPTS * KNN) + nk] = cv;
        ob[(size_t)(DIMS + d) * (NPTS * KNN) + nk] = nv - cv;
    }
}

extern "C" void kernel_launch(void* const* d_in, const int* in_sizes, int n_in,
                              void* d_out, int out_size, void* d_ws, size_t ws_size,
                              hipStream_t stream) {
    const float* pc = (const float*)d_in[0];
    float* out = (float*)d_out;

    // Scratch inside the edge-feature region of d_out (fully overwritten by
    // the edge kernel): pKey 67.1 MB ++ sq 64 KB  (< 134 MB). pcT must NOT
    // live in d_out (edge reads it while writing d_out) -> d_ws.
    u64* pKey = (u64*)d_out;                          // [NCHUNK][B*N][KNN] u64
    float* sq = out + 16777216;                       // byte 67,108,864
    float* outIdxF = out + (size_t)BATCH * 2 * DIMS * NPTS * KNN; // final idx
    float* pcT = (float*)d_ws;                        // 16 MB
    bool useT = ws_size >= (size_t)BATCH * NPTS * DIMS * sizeof(float);

    ef_sq_kernel<<<(BATCH * NPTS) / 256, 256, 0, stream>>>(pc, sq);
    if (useT)
        ef_transpose<<<dim3(NPTS / 64, BATCH), 256, 0, stream>>>(pc, pcT);
    // CE A/B: chunks 0-15 -> f64 min/max CE; chunks 16-31 -> u64 cmp CE.
    ef_knn_partial<true><<<dim3(RN / PBLK, NCHUNK / 2), PBLK, 0, stream>>>(pc, sq, pKey, 0);
    ef_knn_partial<false><<<dim3(RN / PBLK, NCHUNK / 2), PBLK, 0, stream>>>(pc, sq, pKey, NCHUNK / 2);
    ef_knn_merge<<<(BATCH * NPTS * MLANES) / 256, 256, 0, stream>>>(pKey, outIdxF);
    if (useT)
        ef_edge_kernelT<<<(BATCH * NPTS * KNN / 4) / 256, 256, 0, stream>>>(pcT, outIdxF, out);
    else
        ef_edge_kernel<<<(BATCH * NPTS * KNN) / 256, 256, 0, stream>>>(pc, outIdxF, out);
}

// Round 8
// 363.203 us; speedup vs baseline: 1.0475x; 1.0475x over previous
//
#include <hip/hip_runtime.h>

// EdgeFeature kNN (DGCNN): B=4, D=64, N=4096, K=16, fp32 in/out.
// Ranking replicates the numpy fp32 reference pipeline bit-exactly:
//   sq_n  = numpy pairwise_sum (8-accumulator unroll) of fl(x_d^2)
//   dot   = sequential over d of  a = fmaf(x_d, y_d, a)   (einsum axpy w/ FMA)
//   d2    = fl(fl(sq_n + sq_m) - fl(2*dot));  dist = fl(sqrt(max(d2,0)))
//   order = (dist_f32, index) lexicographic (stable top_k tie-break)
// Key pack: (dist_bits << 32) | m. All packed keys are POSITIVE FINITE f64
// bit patterns (numeric order == bit order), so v_min/max_f64 is an exact
// 2-instr u64 compare-exchange. Sentinel = DBL_MAX bits.
//
// R15 (from R14: pk_fma null-to-negative -> scalar loop final; CE A/B null
//      -> CE not critical; occupancy matters only below ~3 waves/SIMD;
//      tail analysis: edge kernel ran at 1 wave/SIMD = the ~115us hog):
//   * edge: 16x thread split -- one thread per (n, k-quad, d-quad);
//     q-major/u-minor mapping keeps idx loads + all stores 1KB/instr
//     coalesced. 1M threads = 64 waves/CU available.
//   * partial: R13 body verbatim, but key[] carried across CPB=2 chunks
//     per block (stage/process/sync/stage/process, one write). pKey
//     traffic halves; grid (32,16) keeps 4 waves/SIMD available.
//   * merge: 16 lists/row -> 16 lanes/row, pure bitonic shfl combine.

#define BATCH 4
#define DIMS 64
#define NPTS 4096
#define KNN 16
#define NCHUNK 32
#define CHLEN 128      // NPTS / NCHUNK
#define GSZ 8          // candidates per group: 8 independent FMA chains
#define RN (BATCH * NPTS)
#define PBLK 512       // partial-kernel block size
#define CPB 2          // chunks per block (carried key)
#define NLISTS (NCHUNK / CPB)   // 16 partial lists per row
#define MLANES 16      // merge lanes per row (one list each)

typedef unsigned long long u64;
typedef unsigned int u32;

__device__ __forceinline__ double sentinel() {
    return __longlong_as_double(0x7FEFFFFFFFFFFFFFLL);   // DBL_MAX bits
}

// ---- kernel 0: per-point squared norm, numpy pairwise_sum order ---------
__global__ __launch_bounds__(256) void ef_sq_kernel(const float* __restrict__ pc,
                                                    float* __restrict__ sq) {
    int gid = blockIdx.x * 256 + threadIdx.x;     // b*NPTS + n
    int b = gid >> 12;
    int n = gid & (NPTS - 1);
    const float* p = pc + (size_t)b * DIMS * NPTS + n;
    float r[8];
#pragma unroll
    for (int j = 0; j < 8; ++j) {
        float v = p[(size_t)j * NPTS];
        r[j] = __fmul_rn(v, v);
    }
#pragma unroll
    for (int i = 8; i < DIMS; i += 8) {
#pragma unroll
        for (int j = 0; j < 8; ++j) {
            float v = p[(size_t)(i + j) * NPTS];
            r[j] = __fadd_rn(r[j], __fmul_rn(v, v));
        }
    }
    float t01 = __fadd_rn(r[0], r[1]);
    float t23 = __fadd_rn(r[2], r[3]);
    float t45 = __fadd_rn(r[4], r[5]);
    float t67 = __fadd_rn(r[6], r[7]);
    sq[gid] = __fadd_rn(__fadd_rn(t01, t23), __fadd_rn(t45, t67));
}

// ---- kernel 0b: transpose pc[b][d][m] -> pcT[(b*N+m)*64+d] --------------
__global__ __launch_bounds__(256) void ef_transpose(const float* __restrict__ pc,
                                                    float* __restrict__ pcT) {
    __shared__ float smT[DIMS][65];               // 65: conflict-free both phases
    int tid = threadIdx.x;
    int m0 = blockIdx.x * 64;
    int b = blockIdx.y;
    const float* pcb = pc + (size_t)b * DIMS * NPTS;
#pragma unroll
    for (int i = 0; i < 16; ++i) {                // load: coalesced over m
        int idx = i * 256 + tid;
        int d = idx >> 6;
        int m = idx & 63;
        smT[d][m] = pcb[(size_t)d * NPTS + m0 + m];
    }
    __syncthreads();
#pragma unroll
    for (int i = 0; i < 16; ++i) {                // store: coalesced over d
        int idx = i * 256 + tid;
        int m = idx >> 6;
        int d = idx & 63;
        pcT[((size_t)b * NPTS + m0 + m) * DIMS + d] = smT[d][m];
    }
}

// ---- kernel 1: per-(row, 2-chunk) partial top-16, LDS-staged candidates -
// R13 hot loop verbatim; key[] carried across CPB=2 chunks, written once.
__global__ __launch_bounds__(PBLK) void ef_knn_partial(const float* __restrict__ pc,
                                                       const float* __restrict__ sq,
                                                       u64* __restrict__ pKey) {
    __shared__ float tile[DIMS][CHLEN];           // 32 KB candidate tile
    __shared__ float tileSq[CHLEN];
    int tid = threadIdx.x;
    int r = blockIdx.x * PBLK + tid;              // global row: b*NPTS + n
    int y = blockIdx.y;                           // list id 0..NLISTS-1
    int b = (blockIdx.x * PBLK) >> 12;            // uniform per block
    int n = r & (NPTS - 1);
    const float* pcb = pc + (size_t)b * DIMS * NPTS;

    // per-lane query row: lane n reads pc[b][d][n] -> coalesced across lanes
    float xr[DIMS];
#pragma unroll
    for (int d = 0; d < DIMS; ++d) xr[d] = pcb[(size_t)d * NPTS + n];
#pragma unroll
    for (int d = 0; d < DIMS; ++d) asm volatile("" : "+v"(xr[d]));
    float sqn = sq[r];

    double key[KNN];
#pragma unroll
    for (int j = 0; j < KNN; ++j) key[j] = sentinel();

#define CE(arr, i, jj) { double lo_ = fmin(arr[i], arr[jj]); double hi_ = fmax(arr[i], arr[jj]); arr[i] = lo_; arr[jj] = hi_; }

    for (int t = 0; t < CPB; ++t) {
        int m0 = (y * CPB + t) * CHLEN;
        if (t) __syncthreads();                   // all readers done w/ tile
        // stage candidate tile [64][128] + its sq row (coalesced float4)
#pragma unroll
        for (int i = 0; i < 4; ++i) {
            int idx = tid + i * PBLK;             // float4 slot, 2048 total
            int d = idx >> 5;                     // 32 float4 per row
            int mq = idx & 31;
            float4 v = *(const float4*)(pcb + (size_t)d * NPTS + m0 + mq * 4);
            *(float4*)&tile[d][mq * 4] = v;
        }
        if (tid < CHLEN / 4)
            *(float4*)&tileSq[tid * 4] =
                *(const float4*)(sq + (size_t)b * NPTS + m0 + tid * 4);
        __syncthreads();

        for (int g = 0; g < CHLEN; g += GSZ) {
            float acc[GSZ];
#pragma unroll
            for (int j = 0; j < GSZ; ++j) acc[j] = 0.f;
            // d-major: two uniform ds_read_b128 per d-step (broadcast) feed
            // 8 independent FMA chains; per-candidate d-order sequential.
#pragma unroll
            for (int d = 0; d < DIMS; ++d) {
                float xv = xr[d];
                float4 lo = *(const float4*)&tile[d][g];
                float4 hi = *(const float4*)&tile[d][g + 4];
                acc[0] = fmaf(xv, lo.x, acc[0]);
                acc[1] = fmaf(xv, lo.y, acc[1]);
                acc[2] = fmaf(xv, lo.z, acc[2]);
                acc[3] = fmaf(xv, lo.w, acc[3]);
                acc[4] = fmaf(xv, hi.x, acc[4]);
                acc[5] = fmaf(xv, hi.y, acc[5]);
                acc[6] = fmaf(xv, hi.z, acc[6]);
                acc[7] = fmaf(xv, hi.w, acc[7]);
            }
            float4 sq_lo = *(const float4*)&tileSq[g];
            float4 sq_hi = *(const float4*)&tileSq[g + 4];
            float sqv[GSZ] = {sq_lo.x, sq_lo.y, sq_lo.z, sq_lo.w,
                              sq_hi.x, sq_hi.y, sq_hi.z, sq_hi.w};
            double s[GSZ];
#pragma unroll
            for (int j = 0; j < GSZ; ++j) {
                int m = m0 + g + j;
                float t1 = __fadd_rn(sqn, sqv[j]);
                float d2 = __fsub_rn(t1, __fmul_rn(2.0f, acc[j]));
                float dist = __fsqrt_rn(fmaxf(d2, 0.f));
                u64 cu = ((u64)__float_as_uint(dist) << 32) | (u64)(u32)m;
                double cand = __longlong_as_double((long long)cu);
                s[j] = (m == n) ? sentinel() : cand;   // self -> sentinel
            }
            // sort8: Batcher odd-even mergesort, 19 CE (exact u64 order)
            CE(s, 0, 1) CE(s, 2, 3) CE(s, 4, 5) CE(s, 6, 7)
            CE(s, 0, 2) CE(s, 1, 3) CE(s, 4, 6) CE(s, 5, 7)
            CE(s, 1, 2) CE(s, 5, 6)
            CE(s, 0, 4) CE(s, 1, 5) CE(s, 2, 6) CE(s, 3, 7)
            CE(s, 2, 4) CE(s, 3, 5)
            CE(s, 1, 2) CE(s, 3, 4) CE(s, 5, 6)
            // bitonic half-clean: merge sorted-8 into sorted key[16]
#pragma unroll
            for (int j = 8; j < 16; ++j) key[j] = fmin(key[j], s[15 - j]);
            // bitonic clean of 16: stages 8,4,2,1
#pragma unroll
            for (int st = 8; st >= 1; st >>= 1) {
#pragma unroll
                for (int j = 0; j < KNN; ++j) {
                    if ((j & st) == 0) {
                        double a = key[j], d = key[j | st];
                        key[j] = fmin(a, d);
                        key[j | st] = fmax(a, d);
                    }
                }
            }
        }
    }
#undef CE

    // layout [y][r][j]: lane writes 128 B contiguous, wave covers 8 KB
    u64* dst = pKey + ((size_t)y * RN + r) * KNN;
#pragma unroll
    for (int j = 0; j < KNN; ++j) dst[j] = (u64)__double_as_longlong(key[j]);
}

// ---- kernel 2: merge 16 sorted lists per row, 16 lanes per row ----------
// Lane s loads list s; 4 shfl_xor rounds of bitonic merge; lane 0 writes.
__global__ __launch_bounds__(256) void ef_knn_merge(const u64* __restrict__ pKey,
                                                    float* __restrict__ outIdxF) {
    int t = blockIdx.x * 256 + threadIdx.x;       // rows * MLANES = 262144
    int r = t >> 4;
    int s = t & 15;
    double key[KNN];
    {
        const u64* src = pKey + ((size_t)s * RN + r) * KNN;
#pragma unroll
        for (int j = 0; j < KNN; ++j)
            key[j] = __longlong_as_double((long long)src[j]);
    }
#pragma unroll
    for (int mask = 1; mask <= 8; mask <<= 1) {
        double oth[KNN];
#pragma unroll
        for (int j = 0; j < KNN; ++j) oth[j] = __shfl_xor(key[j], mask, 64);
#pragma unroll
        for (int j = 0; j < KNN; ++j) key[j] = fmin(key[j], oth[KNN - 1 - j]);
#pragma unroll
        for (int st = 8; st >= 1; st >>= 1) {
#pragma unroll
            for (int j = 0; j < KNN; ++j) {
                if ((j & st) == 0) {
                    double a = key[j], d = key[j | st];
                    key[j] = fmin(a, d);
                    key[j | st] = fmax(a, d);
                }
            }
        }
    }
    if (s == 0) {
        float* dstf = outIdxF + (size_t)r * KNN;
#pragma unroll
        for (int j = 0; j < KNN; ++j)
            dstf[j] = (float)(u32)((u64)__double_as_longlong(key[j]) & 0xFFFFFFFFu);
    }
}

// ---- kernel 3: edge features, 16x split: thread = (n, k-quad, d-quad) ---
// q-major / u-minor: stores and idx loads fully coalesced (1KB/wave/instr).
__global__ __launch_bounds__(256) void ef_edge_kernelT(const float* __restrict__ pcT,
                                                       const float* __restrict__ idxF,
                                                       float* __restrict__ out) {
    int gid = blockIdx.x * 256 + threadIdx.x;      // 1,048,576
    int u = gid & 65535;                           // (b, n, k-quad) unit
    int q = gid >> 16;                             // d-quad 0..15 (block-uniform)
    int b = u >> 14;
    int rem = u & 16383;
    int n = rem >> 2;
    int k0 = (rem & 3) * 4;
    float4 i4 = *(const float4*)(idxF + (((size_t)b << 12) + n) * KNN + k0);
    int m0 = (int)i4.x, m1 = (int)i4.y, m2 = (int)i4.z, m3 = (int)i4.w;
    const float* base = pcT + (((size_t)b << 12)) * DIMS + q * 4;
    float4 c4 = *(const float4*)(base + (size_t)n * DIMS);
    float4 a0 = *(const float4*)(base + (size_t)m0 * DIMS);
    float4 a1 = *(const float4*)(base + (size_t)m1 * DIMS);
    float4 a2 = *(const float4*)(base + (size_t)m2 * DIMS);
    float4 a3 = *(const float4*)(base + (size_t)m3 * DIMS);
    float* ob = out + ((size_t)b * 2 * DIMS + 4 * q) * (NPTS * KNN)
                    + (size_t)n * KNN + k0;
    float cv;
    cv = c4.x;
    *(float4*)(ob + 0 * (size_t)(NPTS * KNN)) = make_float4(cv, cv, cv, cv);
    *(float4*)(ob + (size_t)(DIMS + 0) * (NPTS * KNN)) =
        make_float4(a0.x - cv, a1.x - cv, a2.x - cv, a3.x - cv);
    cv = c4.y;
    *(float4*)(ob + 1 * (size_t)(NPTS * KNN)) = make_float4(cv, cv, cv, cv);
    *(float4*)(ob + (size_t)(DIMS + 1) * (NPTS * KNN)) =
        make_float4(a0.y - cv, a1.y - cv, a2.y - cv, a3.y - cv);
    cv = c4.z;
    *(float4*)(ob + 2 * (size_t)(NPTS * KNN)) = make_float4(cv, cv, cv, cv);
    *(float4*)(ob + (size_t)(DIMS + 2) * (NPTS * KNN)) =
        make_float4(a0.z - cv, a1.z - cv, a2.z - cv, a3.z - cv);
    cv = c4.w;
    *(float4*)(ob + 3 * (size_t)(NPTS * KNN)) = make_float4(cv, cv, cv, cv);
    *(float4*)(ob + (size_t)(DIMS + 3) * (NPTS * KNN)) =
        make_float4(a0.w - cv, a1.w - cv, a2.w - cv, a3.w - cv);
}

// ---- kernel 3 fallback: edge features straight from pc ------------------
__global__ __launch_bounds__(256) void ef_edge_kernel(const float* __restrict__ pc,
                                                      const float* __restrict__ idxF,
                                                      float* __restrict__ out) {
    int gid = blockIdx.x * 256 + threadIdx.x;      // B*N*K = 262144
    int b = gid >> 16;                             // N*K = 65536
    int nk = gid & 65535;
    int n = nk >> 4;
    int m = (int)idxF[gid];
    const float* pcb = pc + (size_t)b * DIMS * NPTS;
    float* ob = out + (size_t)b * 2 * DIMS * NPTS * KNN;
#pragma unroll
    for (int d = 0; d < DIMS; ++d) {
        float cv = pcb[(size_t)d * NPTS + n];
        float nv = pcb[(size_t)d * NPTS + m];
        ob[(size_t)d * (NPTS * KNN) + nk] = cv;
        ob[(size_t)(DIMS + d) * (NPTS * KNN) + nk] = nv - cv;
    }
}

extern "C" void kernel_launch(void* const* d_in, const int* in_sizes, int n_in,
                              void* d_out, int out_size, void* d_ws, size_t ws_size,
                              hipStream_t stream) {
    const float* pc = (const float*)d_in[0];
    float* out = (float*)d_out;

    // Scratch inside the edge-feature region of d_out (fully overwritten by
    // the edge kernel): pKey 33.5 MB ++ sq 64 KB  (< 134 MB). pcT must NOT
    // live in d_out (edge reads it while writing d_out) -> d_ws.
    u64* pKey = (u64*)d_out;                          // [NLISTS][B*N][KNN] u64
    float* sq = out + 16777216;                       // byte 67,108,864
    float* outIdxF = out + (size_t)BATCH * 2 * DIMS * NPTS * KNN; // final idx
    float* pcT = (float*)d_ws;                        // 16 MB
    bool useT = ws_size >= (size_t)BATCH * NPTS * DIMS * sizeof(float);

    ef_sq_kernel<<<(BATCH * NPTS) / 256, 256, 0, stream>>>(pc, sq);
    if (useT)
        ef_transpose<<<dim3(NPTS / 64, BATCH), 256, 0, stream>>>(pc, pcT);
    ef_knn_partial<<<dim3(RN / PBLK, NLISTS), PBLK, 0, stream>>>(pc, sq, pKey);
    ef_knn_merge<<<(RN * MLANES) / 256, 256, 0, stream>>>(pKey, outIdxF);
    if (useT)
        ef_edge_kernelT<<<(BATCH * NPTS * KNN * 16 / 4) / 256, 256, 0, stream>>>(pcT, outIdxF, out);
    else
        ef_edge_kernel<<<(BATCH * NPTS * KNN) / 256, 256, 0, stream>>>(pc, outIdxF, out);
}

// Round 9
// 314.037 us; speedup vs baseline: 1.2115x; 1.1566x over previous
//
#include <hip/hip_runtime.h>

// EdgeFeature kNN (DGCNN): B=4, D=64, N=4096, K=16, fp32 in/out.
// Ranking replicates the numpy fp32 reference pipeline bit-exactly:
//   sq_n  = numpy pairwise_sum (8-accumulator unroll) of fl(x_d^2)
//   dot   = sequential over d of  a = fmaf(x_d, y_d, a)   (einsum axpy w/ FMA)
//   d2    = fl(fl(sq_n + sq_m) - fl(2*dot));  dist = fl(sqrt(max(d2,0)))
//   order = (dist_f32, index) lexicographic (stable top_k tie-break)
// Key pack: (dist_bits << 32) | m. All packed keys are POSITIVE FINITE f64
// bit patterns (numeric order == bit order), so v_min/max_f64 is an exact
// 2-instr u64 compare-exchange. Sentinel = DBL_MAX bits.
//
// R16 (from R15: carried-key partial regressed (fewer blocks, extra sync)
//      -> revert to R10-exact partial (185us measured). Tail ~129us was
//      CONSTANT across 3 edge designs: R11-style had amp-1 reads but
//      1 wave/SIMD; R15-split had 16 waves/CU but 4x line amplification
//      (16B granule reads, line shared across blocks)):
//   * edge v3: thread = (b,n,k). Own neighbor row read sequentially
//     (16 x float4, row 256B-aligned -> amp-1, L1 line reuse) AND
//     262144 threads = 16 waves/CU. Stores scalar but fully coalesced:
//     wave = 4n x 16k -> 256 contiguous floats per store instr.
//   * partial: R10-exact body (PBLK=256, bounds (256,3), 32 chunks).
//   * merge: R13 8-lane version verbatim.

#define BATCH 4
#define DIMS 64
#define NPTS 4096
#define KNN 16
#define NCHUNK 32
#define CHLEN 128      // NPTS / NCHUNK
#define GSZ 8          // candidates per group: 8 independent FMA chains
#define RN (BATCH * NPTS)
#define MLANES 8       // merge lanes per row
#define MCH (NCHUNK / MLANES)

typedef unsigned long long u64;
typedef unsigned int u32;

__device__ __forceinline__ double sentinel() {
    return __longlong_as_double(0x7FEFFFFFFFFFFFFFLL);   // DBL_MAX bits
}

// ---- kernel 0: per-point squared norm, numpy pairwise_sum order ---------
__global__ __launch_bounds__(256) void ef_sq_kernel(const float* __restrict__ pc,
                                                    float* __restrict__ sq) {
    int gid = blockIdx.x * 256 + threadIdx.x;     // b*NPTS + n
    int b = gid >> 12;
    int n = gid & (NPTS - 1);
    const float* p = pc + (size_t)b * DIMS * NPTS + n;
    float r[8];
#pragma unroll
    for (int j = 0; j < 8; ++j) {
        float v = p[(size_t)j * NPTS];
        r[j] = __fmul_rn(v, v);
    }
#pragma unroll
    for (int i = 8; i < DIMS; i += 8) {
#pragma unroll
        for (int j = 0; j < 8; ++j) {
            float v = p[(size_t)(i + j) * NPTS];
            r[j] = __fadd_rn(r[j], __fmul_rn(v, v));
        }
    }
    float t01 = __fadd_rn(r[0], r[1]);
    float t23 = __fadd_rn(r[2], r[3]);
    float t45 = __fadd_rn(r[4], r[5]);
    float t67 = __fadd_rn(r[6], r[7]);
    sq[gid] = __fadd_rn(__fadd_rn(t01, t23), __fadd_rn(t45, t67));
}

// ---- kernel 0b: transpose pc[b][d][m] -> pcT[(b*N+m)*64+d] --------------
__global__ __launch_bounds__(256) void ef_transpose(const float* __restrict__ pc,
                                                    float* __restrict__ pcT) {
    __shared__ float smT[DIMS][65];               // 65: conflict-free both phases
    int tid = threadIdx.x;
    int m0 = blockIdx.x * 64;
    int b = blockIdx.y;
    const float* pcb = pc + (size_t)b * DIMS * NPTS;
#pragma unroll
    for (int i = 0; i < 16; ++i) {                // load: coalesced over m
        int idx = i * 256 + tid;
        int d = idx >> 6;
        int m = idx & 63;
        smT[d][m] = pcb[(size_t)d * NPTS + m0 + m];
    }
    __syncthreads();
#pragma unroll
    for (int i = 0; i < 16; ++i) {                // store: coalesced over d
        int idx = i * 256 + tid;
        int m = idx >> 6;
        int d = idx & 63;
        pcT[((size_t)b * NPTS + m0 + m) * DIMS + d] = smT[d][m];
    }
}

// ---- kernel 1: per-(row, chunk) partial top-16, LDS-staged candidates ---
// R10-exact configuration (best measured: 185 us).
__global__ __launch_bounds__(256, 3) void ef_knn_partial(const float* __restrict__ pc,
                                                         const float* __restrict__ sq,
                                                         u64* __restrict__ pKey) {
    __shared__ float tile[DIMS][CHLEN];           // 32 KB candidate tile
    __shared__ float tileSq[CHLEN];
    int tid = threadIdx.x;
    int r = blockIdx.x * 256 + tid;               // global row: b*NPTS + n
    int c = blockIdx.y;
    int b = (blockIdx.x * 256) >> 12;             // uniform per block
    int n = r & (NPTS - 1);
    int m0 = c * CHLEN;
    const float* pcb = pc + (size_t)b * DIMS * NPTS;

    // per-lane query row: lane n reads pc[b][d][n] -> coalesced across lanes
    float xr[DIMS];
#pragma unroll
    for (int d = 0; d < DIMS; ++d) xr[d] = pcb[(size_t)d * NPTS + n];
    // pin: anchor xr (R9: compiler re-loaded xr per group without this)
#pragma unroll
    for (int d = 0; d < DIMS; ++d) asm volatile("" : "+v"(xr[d]));
    float sqn = sq[r];

    // stage candidate tile [64][128] + its sq row (coalesced float4)
#pragma unroll
    for (int i = 0; i < 8; ++i) {
        int idx = tid + i * 256;                  // float4 slot, 2048 total
        int d = idx >> 5;                         // 32 float4 per row
        int mq = idx & 31;
        float4 v = *(const float4*)(pcb + (size_t)d * NPTS + m0 + mq * 4);
        *(float4*)&tile[d][mq * 4] = v;
    }
    if (tid < CHLEN / 4)
        *(float4*)&tileSq[tid * 4] =
            *(const float4*)(sq + (size_t)b * NPTS + m0 + tid * 4);
    __syncthreads();

    double key[KNN];
#pragma unroll
    for (int j = 0; j < KNN; ++j) key[j] = sentinel();

#define CE(arr, i, jj) { double lo_ = fmin(arr[i], arr[jj]); double hi_ = fmax(arr[i], arr[jj]); arr[i] = lo_; arr[jj] = hi_; }

    for (int g = 0; g < CHLEN; g += GSZ) {
        float acc[GSZ];
#pragma unroll
        for (int j = 0; j < GSZ; ++j) acc[j] = 0.f;
        // d-major: two uniform ds_read_b128 per d-step (broadcast) feed 8
        // independent FMA chains; per-candidate d-order sequential (exact).
#pragma unroll
        for (int d = 0; d < DIMS; ++d) {
            float xv = xr[d];
            float4 lo = *(const float4*)&tile[d][g];
            float4 hi = *(const float4*)&tile[d][g + 4];
            acc[0] = fmaf(xv, lo.x, acc[0]);
            acc[1] = fmaf(xv, lo.y, acc[1]);
            acc[2] = fmaf(xv, lo.z, acc[2]);
            acc[3] = fmaf(xv, lo.w, acc[3]);
            acc[4] = fmaf(xv, hi.x, acc[4]);
            acc[5] = fmaf(xv, hi.y, acc[5]);
            acc[6] = fmaf(xv, hi.z, acc[6]);
            acc[7] = fmaf(xv, hi.w, acc[7]);
        }
        float4 sq_lo = *(const float4*)&tileSq[g];
        float4 sq_hi = *(const float4*)&tileSq[g + 4];
        float sqv[GSZ] = {sq_lo.x, sq_lo.y, sq_lo.z, sq_lo.w,
                          sq_hi.x, sq_hi.y, sq_hi.z, sq_hi.w};
        double s[GSZ];
#pragma unroll
        for (int j = 0; j < GSZ; ++j) {
            int m = m0 + g + j;
            float t1 = __fadd_rn(sqn, sqv[j]);
            float d2 = __fsub_rn(t1, __fmul_rn(2.0f, acc[j]));
            float dist = __fsqrt_rn(fmaxf(d2, 0.f));
            u64 cu = ((u64)__float_as_uint(dist) << 32) | (u64)(u32)m;
            double cand = __longlong_as_double((long long)cu);
            s[j] = (m == n) ? sentinel() : cand;   // self -> +max sentinel
        }
        // sort8: Batcher odd-even mergesort, 19 CE (exact u64 order via f64)
        CE(s, 0, 1) CE(s, 2, 3) CE(s, 4, 5) CE(s, 6, 7)
        CE(s, 0, 2) CE(s, 1, 3) CE(s, 4, 6) CE(s, 5, 7)
        CE(s, 1, 2) CE(s, 5, 6)
        CE(s, 0, 4) CE(s, 1, 5) CE(s, 2, 6) CE(s, 3, 7)
        CE(s, 2, 4) CE(s, 3, 5)
        CE(s, 1, 2) CE(s, 3, 4) CE(s, 5, 6)
        // bitonic half-clean: merge sorted-8 into sorted key[16]
#pragma unroll
        for (int j = 8; j < 16; ++j) key[j] = fmin(key[j], s[15 - j]);
        // bitonic clean of 16: stages 8,4,2,1
#pragma unroll
        for (int st = 8; st >= 1; st >>= 1) {
#pragma unroll
            for (int j = 0; j < KNN; ++j) {
                if ((j & st) == 0) {
                    double a = key[j], d = key[j | st];
                    key[j] = fmin(a, d);
                    key[j | st] = fmax(a, d);
                }
            }
        }
    }
#undef CE

    // layout [c][r][j]: lane writes 128 B contiguous, wave covers 8 KB
    u64* dst = pKey + ((size_t)c * RN + r) * KNN;
#pragma unroll
    for (int j = 0; j < KNN; ++j) dst[j] = (u64)__double_as_longlong(key[j]);
}

// ---- kernel 2: merge 32 sorted partial lists per row, 8 lanes per row ---
__global__ __launch_bounds__(256) void ef_knn_merge(const u64* __restrict__ pKey,
                                                    float* __restrict__ outIdxF) {
    int t = blockIdx.x * 256 + threadIdx.x;       // rows * MLANES = 131072
    int r = t >> 3;
    int s = t & 7;
    double key[KNN];
    {
        const u64* src = pKey + ((size_t)(s * MCH) * RN + r) * KNN;
#pragma unroll
        for (int j = 0; j < KNN; ++j)
            key[j] = __longlong_as_double((long long)src[j]);
    }
    for (int ci = 1; ci < MCH; ++ci) {
        const u64* src = pKey + ((size_t)(s * MCH + ci) * RN + r) * KNN;
        double v[KNN];
#pragma unroll
        for (int j = 0; j < KNN; ++j)
            v[j] = __longlong_as_double((long long)src[j]);
#pragma unroll
        for (int j = 0; j < KNN; ++j) key[j] = fmin(key[j], v[KNN - 1 - j]);
#pragma unroll
        for (int st = 8; st >= 1; st >>= 1) {
#pragma unroll
            for (int j = 0; j < KNN; ++j) {
                if ((j & st) == 0) {
                    double a = key[j], d = key[j | st];
                    key[j] = fmin(a, d);
                    key[j | st] = fmax(a, d);
                }
            }
        }
    }
#pragma unroll
    for (int mask = 1; mask <= 4; mask <<= 1) {
        double oth[KNN];
#pragma unroll
        for (int j = 0; j < KNN; ++j) oth[j] = __shfl_xor(key[j], mask, 64);
#pragma unroll
        for (int j = 0; j < KNN; ++j) key[j] = fmin(key[j], oth[KNN - 1 - j]);
#pragma unroll
        for (int st = 8; st >= 1; st >>= 1) {
#pragma unroll
            for (int j = 0; j < KNN; ++j) {
                if ((j & st) == 0) {
                    double a = key[j], d = key[j | st];
                    key[j] = fmin(a, d);
                    key[j | st] = fmax(a, d);
                }
            }
        }
    }
    if (s == 0) {
        float* dstf = outIdxF + (size_t)r * KNN;
#pragma unroll
        for (int j = 0; j < KNN; ++j)
            dstf[j] = (float)(u32)((u64)__double_as_longlong(key[j]) & 0xFFFFFFFFu);
    }
}

// ---- kernel 3: edge features v3 -----------------------------------------
// Thread = (b,n,k): own neighbor row read sequentially (amp-1, L1 reuse),
// 262144 threads = 16 waves/CU. Scalar stores, wave = 4n x 16k -> each
// store instr covers 256 contiguous floats (fully coalesced).
__global__ __launch_bounds__(256) void ef_edge_kernelT(const float* __restrict__ pcT,
                                                       const float* __restrict__ idxF,
                                                       float* __restrict__ out) {
    int gid = blockIdx.x * 256 + threadIdx.x;      // B*N*K = 262144
    int k = gid & 15;
    int n = (gid >> 4) & (NPTS - 1);
    int b = gid >> 16;
    int m = (int)idxF[gid];                        // idxF[(b*N+n)*16+k] = [gid]
    const float* crow = pcT + ((size_t)(b << 12) + n) * DIMS;
    const float* nrow = pcT + ((size_t)(b << 12) + m) * DIMS;
    float* ob = out + (size_t)b * 2 * DIMS * NPTS * KNN + (size_t)n * KNN + k;
#pragma unroll
    for (int q = 0; q < DIMS / 4; ++q) {
        float4 c4 = *(const float4*)(crow + q * 4);
        float4 a4 = *(const float4*)(nrow + q * 4);
        ob[(size_t)(4 * q + 0) * (NPTS * KNN)] = c4.x;
        ob[(size_t)(4 * q + 1) * (NPTS * KNN)] = c4.y;
        ob[(size_t)(4 * q + 2) * (NPTS * KNN)] = c4.z;
        ob[(size_t)(4 * q + 3) * (NPTS * KNN)] = c4.w;
        ob[(size_t)(DIMS + 4 * q + 0) * (NPTS * KNN)] = a4.x - c4.x;
        ob[(size_t)(DIMS + 4 * q + 1) * (NPTS * KNN)] = a4.y - c4.y;
        ob[(size_t)(DIMS + 4 * q + 2) * (NPTS * KNN)] = a4.z - c4.z;
        ob[(size_t)(DIMS + 4 * q + 3) * (NPTS * KNN)] = a4.w - c4.w;
    }
}

// ---- kernel 3 fallback: edge features straight from pc ------------------
__global__ __launch_bounds__(256) void ef_edge_kernel(const float* __restrict__ pc,
                                                      const float* __restrict__ idxF,
                                                      float* __restrict__ out) {
    int gid = blockIdx.x * 256 + threadIdx.x;      // B*N*K = 262144
    int b = gid >> 16;                             // N*K = 65536
    int nk = gid & 65535;
    int n = nk >> 4;
    int m = (int)idxF[gid];
    const float* pcb = pc + (size_t)b * DIMS * NPTS;
    float* ob = out + (size_t)b * 2 * DIMS * NPTS * KNN;
#pragma unroll
    for (int d = 0; d < DIMS; ++d) {
        float cv = pcb[(size_t)d * NPTS + n];
        float nv = pcb[(size_t)d * NPTS + m];
        ob[(size_t)d * (NPTS * KNN) + nk] = cv;
        ob[(size_t)(DIMS + d) * (NPTS * KNN) + nk] = nv - cv;
    }
}

extern "C" void kernel_launch(void* const* d_in, const int* in_sizes, int n_in,
                              void* d_out, int out_size, void* d_ws, size_t ws_size,
                              hipStream_t stream) {
    const float* pc = (const float*)d_in[0];
    float* out = (float*)d_out;

    // Scratch inside the edge-feature region of d_out (fully overwritten by
    // the edge kernel): pKey 67.1 MB ++ sq 64 KB  (< 134 MB). pcT must NOT
    // live in d_out (edge reads it while writing d_out) -> d_ws.
    u64* pKey = (u64*)d_out;                          // [NCHUNK][B*N][KNN] u64
    float* sq = out + 16777216;                       // byte 67,108,864
    float* outIdxF = out + (size_t)BATCH * 2 * DIMS * NPTS * KNN; // final idx
    float* pcT = (float*)d_ws;                        // 16 MB
    bool useT = ws_size >= (size_t)BATCH * NPTS * DIMS * sizeof(float);

    ef_sq_kernel<<<(BATCH * NPTS) / 256, 256, 0, stream>>>(pc, sq);
    if (useT)
        ef_transpose<<<dim3(NPTS / 64, BATCH), 256, 0, stream>>>(pc, pcT);
    ef_knn_partial<<<dim3(RN / 256, NCHUNK), 256, 0, stream>>>(pc, sq, pKey);
    ef_knn_merge<<<(RN * MLANES) / 256, 256, 0, stream>>>(pKey, outIdxF);
    if (useT)
        ef_edge_kernelT<<<(BATCH * NPTS * KNN) / 256, 256, 0, stream>>>(pcT, outIdxF, out);
    else
        ef_edge_kernel<<<(BATCH * NPTS * KNN) / 256, 256, 0, stream>>>(pc, outIdxF, out);
}